// Round 4
// baseline (212.820 us; speedup 1.0000x reference)
//
#include <hip/hip_runtime.h>

// B=8, H=8, L=2048, D=64, num_delays=16
static constexpr int LSEQ = 2048;
static constexpr int NB   = 8;
static constexpr int NH   = 8;
static constexpr int ND   = 64;
static constexpr int NDEL = 16;

// ws layout (same 8.4 MB proven-safe envelope, same w/delay offsets):
//   Pc    : float2[128 part][8 b][1024]  at 0      (exactly 8 MiB)
//           compact partial spectra: slot j in [1,1024) holds freq j;
//           slot 0 packs (Re S[0], Re S[1024]) — both freqs are purely real.
//           After reduce_S, part 0 holds the reduced compact spectrum.
//   w     : float [8][16]               at 8388608
//   delay : int   [8][16]               at 8389120
static constexpr size_t WS_P_OFF     = 0;
static constexpr size_t WS_W_OFF     = 8388608;
static constexpr size_t WS_DELAY_OFF = 8389120;

// LDS bank swizzle on float2 index (ifft_topk only): fold bits 4..6 into 1..3.
__device__ __forceinline__ int SWZ(int x) { return x ^ (((x >> 4) & 7) << 1); }

// digit-reversed position of frequency f (radices 8,8,8,4 DIF) and inverse
// (ifft_topk's verified pipeline — unchanged)
__device__ __forceinline__ int pof(int f) {
    return ((f & 7) << 8) | (((f >> 3) & 7) << 5) | (((f >> 6) & 7) << 2) | (f >> 9);
}
__device__ __forceinline__ int fofp(int p) {
    return (p >> 8) | (((p >> 5) & 7) << 3) | (((p >> 2) & 7) << 6) | ((p & 3) << 9);
}

#define CMUL(ar, ai, br, bi) make_float2((ar)*(br) - (ai)*(bi), (ar)*(bi) + (ai)*(br))

__device__ __forceinline__ float2 cmulf(float2 a, float2 b) {
    return make_float2(a.x * b.x - a.y * b.y, a.x * b.y + a.y * b.x);
}

// 5-bit bit reversal (compile-time under unrolled loops)
__device__ __forceinline__ constexpr int BR5(int x) {
    return ((x & 1) << 4) | ((x & 2) << 2) | (x & 4) | ((x & 8) >> 2) | ((x & 16) >> 4);
}

// in-register DIF-32 (natural in, bit-reversed out: pos p holds A[BR5(p)])
__device__ __forceinline__ void fft32_dif(float2 z[32]) {
    constexpr float WR[16] = {
        1.f,           0.980785280f,  0.923879533f,  0.831469612f,
        0.707106781f,  0.555570233f,  0.382683432f,  0.195090322f,
        0.f,          -0.195090322f, -0.382683432f, -0.555570233f,
       -0.707106781f, -0.831469612f, -0.923879533f, -0.980785280f };
    constexpr float WI[16] = {
       -0.f,          -0.195090322f, -0.382683432f, -0.555570233f,
       -0.707106781f, -0.831469612f, -0.923879533f, -0.980785280f,
       -1.f,          -0.980785280f, -0.923879533f, -0.831469612f,
       -0.707106781f, -0.555570233f, -0.382683432f, -0.195090322f };
    #pragma unroll
    for (int s = 0; s < 5; ++s) {
        const int hh = 16 >> s;
        #pragma unroll
        for (int b0 = 0; b0 < 32; b0 += 2 * hh) {
            #pragma unroll
            for (int u = 0; u < hh; ++u) {
                const float2 a = z[b0 + u], bb = z[b0 + u + hh];
                z[b0 + u] = make_float2(a.x + bb.x, a.y + bb.y);
                const float dx = a.x - bb.x, dy = a.y - bb.y;
                const int ti = u << s;                  // w_M^u = w_32^{u*2^s}
                z[b0 + u + hh] = (ti == 0) ? make_float2(dx, dy)
                    : make_float2(dx * WR[ti] - dy * WI[ti],
                                  dx * WI[ti] + dy * WR[ti]);
            }
        }
    }
}

// C[f] from Z[f], Z[2048-f] for packed z = q + i*k (verified in prior rounds)
__device__ __forceinline__ float2 corrprod(float2 Zf, float2 Zm) {
    const float qr = 0.5f * (Zf.x + Zm.x), qi = 0.5f * (Zf.y - Zm.y);
    const float kr = 0.5f * (Zf.y + Zm.y), ki = 0.5f * (Zm.x - Zf.x);
    return make_float2(qr * kr + qi * ki, qi * kr - qr * ki);
}

// ---------------------------------------------------------------------------
// Kernel A (rewritten): WAVE-AUTONOMOUS register FFT. Block = (bh, dgrp of 4
// d-channels), one 2048-pt packed FFT (z = q_d + i*k_d) per wave, data in
// 32 float2 registers/lane. Four-step: n = 64*j + L (j=reg, L=lane):
//   1) in-lane DIF-32 over j (literal twiddles)    -> pos p holds A[BR5(p)]
//   2) twiddle w_2048^{L*k1} (chained powers)
//   3) cross-lane DIF-64 over L: 6 shfl_xor stages -> lane L holds k2=br6(L)
//   Z[f] at (reg p, lane L), f = BR5(p) + 32*br6(L).
// Mirror for product: Z[2048-f] = shfl_xor(z[BR5(32-k1)], 63) — one shuffle.
// NO __syncthreads in the FFT (round-3 showed the barrier-phased LDS pipeline
// caps the machine at ~5 runnable waves/CU; this decouples waves entirely).
// LDS (32 KiB) only for: 2-pass coalesced load transpose + 4-wave reduction.
// Compact partial layout/part count (128) identical to round-3.
// ---------------------------------------------------------------------------
__global__ __launch_bounds__(256, 2) void fft_corr(const float* __restrict__ q,
                                                   const float* __restrict__ k,
                                                   float2* __restrict__ Pc) {
    __shared__ float2 lds[4096];        // staging [4 d][1024 n] / planes [4 w][1024 f]
    const int t  = threadIdx.x;
    const int w  = t >> 6;              // wave id = local d-channel
    const int L  = t & 63;
    const int bi = blockIdx.x;          // 1024 = 8 xcd * 8 bh * 16 dgrp
    const int xcd  = bi & 7;
    const int sl   = bi >> 3;           // 0..127
    const int bh   = xcd * 8 + (sl >> 4);
    const int dgrp = sl & 15;
    const int b    = bh >> 3;
    const int h    = bh & 7;
    const size_t base = (size_t)bh * (LSEQ * ND) + (size_t)(dgrp * 4);

    float2 z[32];

    // ---- staging: two n-halves through LDS (coalesced float4 loads) ----
    #pragma unroll
    for (int P = 0; P < 2; ++P) {
        float4 q4[4], k4[4];
        #pragma unroll
        for (int u = 0; u < 4; ++u) {
            const int n = P * 1024 + t + 256 * u;
            const size_t r = base + (size_t)n * ND;
            q4[u] = *(const float4*)(q + r);
            k4[u] = *(const float4*)(k + r);
        }
        if (P) __syncthreads();         // pass-0 reads done before overwrite
        #pragma unroll
        for (int u = 0; u < 4; ++u) {
            const int nn = t + 256 * u;
            #pragma unroll
            for (int c = 0; c < 4; ++c)
                lds[c * 1024 + nn] = make_float2((&q4[u].x)[c], (&k4[u].x)[c]);
        }
        __syncthreads();
        #pragma unroll
        for (int jj = 0; jj < 16; ++jj)
            z[16 * P + jj] = lds[w * 1024 + 64 * jj + L];   // z[j] = x[64j+L]
    }
    __syncthreads();                    // all staging reads done (LDS reused below)

    // ---- step 1: in-lane DIF-32 ----
    fft32_dif(z);

    // ---- step 2: twiddle w_2048^{L*k1}, k1 = BR5(p) ----
    {
        float sn, cs;
        __sincosf(-6.28318530717958647692f * (float)L / 2048.f, &sn, &cs);
        const float2 W1 = make_float2(cs, sn);
        float2 Wc = W1;
        z[BR5(1)] = cmulf(z[BR5(1)], Wc);
        #pragma unroll
        for (int m = 2; m < 32; ++m) {
            Wc = cmulf(Wc, W1);
            z[BR5(m)] = cmulf(z[BR5(m)], Wc);
        }
    }

    // ---- step 3: cross-lane DIF-64 over lanes (6 shfl_xor stages) ----
    #pragma unroll
    for (int s = 0; s < 6; ++s) {
        const int hh = 32 >> s;
        float ts, tc;
        __sincosf(-6.28318530717958647692f * (float)(L & (hh - 1)) /
                      (float)(64 >> s), &ts, &tc);
        const bool bot = (L & hh) != 0;
        #pragma unroll
        for (int p = 0; p < 32; ++p) {
            const float ex = __shfl_xor(z[p].x, hh);
            const float ey = __shfl_xor(z[p].y, hh);
            const float ax = z[p].x + ex, ay = z[p].y + ey;
            const float sx = ex - z[p].x, sy = ey - z[p].y;
            const float bx = sx * tc - sy * ts;
            const float by = sx * ts + sy * tc;
            z[p].x = bot ? bx : ax;
            z[p].y = bot ? by : ay;
        }
    }

    // ---- product Q*conj(K), compact store to LDS plane w (swizzled) ----
    const int kk2 = (int)(__brev((unsigned)L) >> 26);      // br6(L) = k2
    const bool own = (L & 1) == 0;                          // owners hold f<1024
    {
        // p=0 (k1=0): mirror is f=32*((64-k2)&63) — gather via bpermute
        const int mlane = (int)(__brev((unsigned)((64 - kk2) & 63)) >> 26);
        const float zmx = __shfl(z[0].x, mlane);
        const float zmy = __shfl(z[0].y, mlane);
        float2 c = corrprod(z[0], make_float2(zmx, zmy));
        const float c1024 = __shfl(c.x, 1);                 // lane1 holds f=1024
        if (L == 0) c.y = c1024;                            // pack (C0, C1024)
        if (own) lds[w * 1024 + ((kk2 << 5) | kk2)] = c;
    }
    #pragma unroll
    for (int p = 1; p < 32; ++p) {
        const int k1 = BR5(p);
        const int pm = BR5(32 - k1);                        // reg holding 32-k1
        const float zmx = __shfl_xor(z[pm].x, 63);          // mirror lane = L^63
        const float zmy = __shfl_xor(z[pm].y, 63);
        const float2 c = corrprod(z[p], make_float2(zmx, zmy));
        if (own) lds[w * 1024 + ((kk2 << 5) | (k1 ^ kk2))] = c;
    }
    __syncthreads();

    // ---- sum the 4 wave-planes, store compact partial (coalesced) ----
    float2* Pp = Pc + (size_t)(h * 16 + dgrp) * (NB * 1024) + (size_t)b * 1024;
    #pragma unroll
    for (int u = 0; u < 4; ++u) {
        const int sidx = t + 256 * u;
        const int sw = (sidx & ~31) | ((sidx & 31) ^ ((sidx >> 5) & 31));
        float ax = 0.f, ay = 0.f;
        #pragma unroll
        for (int w4 = 0; w4 < 4; ++w4) {
            const float2 v = lds[w4 * 1024 + sw];
            ax += v.x; ay += v.y;
        }
        Pp[sidx] = make_float2(ax, ay);
    }
}

// ---------------------------------------------------------------------------
// Reduce 128 compact partials IN-PLACE into part 0. 128 blocks; each block
// owns 64 columns, 4 part-slices of 32 summed per thread then LDS tree —
// 32 loads/thread (round-3's 32-block/128-load version was latency-bound).
// ---------------------------------------------------------------------------
__global__ __launch_bounds__(256) void reduce_S(float2* __restrict__ Pc) {
    __shared__ float2 acc[256];
    const int t     = threadIdx.x;
    const int col   = blockIdx.x * 64 + (t & 63);    // 0..8191 = b*1024+j
    const int slice = t >> 6;                        // 4 slices x 32 parts
    float ax = 0.f, ay = 0.f;
    #pragma unroll 8
    for (int pp = 0; pp < 32; ++pp) {
        const float2 v = Pc[(size_t)(slice * 32 + pp) * (NB * 1024) + col];
        ax += v.x; ay += v.y;
    }
    acc[t] = make_float2(ax, ay);
    __syncthreads();
    if (t < 64) {
        const float2 r0 = acc[t], r1 = acc[t + 64], r2 = acc[t + 128], r3 = acc[t + 192];
        Pc[col] = make_float2(r0.x + r1.x + r2.x + r3.x, r0.y + r1.y + r2.y + r3.y);
    }
}

// ---------------------------------------------------------------------------
// Kernel B: block per batch, 256 threads. Loads the COMPACT reduced spectrum
// (1024 float2), reconstructs the full conj-symmetric digit-rev spectrum in
// LDS, then inverse FFT via conj trick on the verified mixed-radix pipeline:
// irfft(S)[tau] = Re(FFT_fwd(conj(S))[tau])/N. 16-iter argmax top-k + softmax.
// (unchanged from round-3 passing version)
// ---------------------------------------------------------------------------
__device__ __forceinline__ void dft8(const float2 x[8], float2 X[8]) {
    const float RH = 0.70710678118654752440f;
    float2 a0 = make_float2(x[0].x + x[4].x, x[0].y + x[4].y);
    float2 a1 = make_float2(x[1].x + x[5].x, x[1].y + x[5].y);
    float2 a2 = make_float2(x[2].x + x[6].x, x[2].y + x[6].y);
    float2 a3 = make_float2(x[3].x + x[7].x, x[3].y + x[7].y);
    float2 b0 = make_float2(x[0].x - x[4].x, x[0].y - x[4].y);
    float  t1r = x[1].x - x[5].x, t1i = x[1].y - x[5].y;
    float2 b1 = make_float2(RH * (t1r + t1i), RH * (t1i - t1r));
    float  t2r = x[2].x - x[6].x, t2i = x[2].y - x[6].y;
    float2 b2 = make_float2(t2i, -t2r);
    float  t3r = x[3].x - x[7].x, t3i = x[3].y - x[7].y;
    float2 b3 = make_float2(RH * (t3i - t3r), -RH * (t3r + t3i));
    float2 c0 = make_float2(a0.x + a2.x, a0.y + a2.y);
    float2 d0 = make_float2(a0.x - a2.x, a0.y - a2.y);
    float2 c1 = make_float2(a1.x + a3.x, a1.y + a3.y);
    float2 d1 = make_float2(a1.y - a3.y, -(a1.x - a3.x));
    X[0] = make_float2(c0.x + c1.x, c0.y + c1.y);
    X[4] = make_float2(c0.x - c1.x, c0.y - c1.y);
    X[2] = make_float2(d0.x + d1.x, d0.y + d1.y);
    X[6] = make_float2(d0.x - d1.x, d0.y - d1.y);
    float2 e0 = make_float2(b0.x + b2.x, b0.y + b2.y);
    float2 f0 = make_float2(b0.x - b2.x, b0.y - b2.y);
    float2 e1 = make_float2(b1.x + b3.x, b1.y + b3.y);
    float2 f1 = make_float2(b1.y - b3.y, -(b1.x - b3.x));
    X[1] = make_float2(e0.x + e1.x, e0.y + e1.y);
    X[5] = make_float2(e0.x - e1.x, e0.y - e1.y);
    X[3] = make_float2(f0.x + f1.x, f0.y + f1.y);
    X[7] = make_float2(f0.x - f1.x, f0.y - f1.y);
}

__device__ __forceinline__ void dft4(const float2 x[4], float2 X[4]) {
    float2 s0 = make_float2(x[0].x + x[2].x, x[0].y + x[2].y);
    float2 s1 = make_float2(x[1].x + x[3].x, x[1].y + x[3].y);
    float2 d0 = make_float2(x[0].x - x[2].x, x[0].y - x[2].y);
    float2 d1 = make_float2(x[1].y - x[3].y, -(x[1].x - x[3].x));
    X[0] = make_float2(s0.x + s1.x, s0.y + s1.y);
    X[2] = make_float2(s0.x - s1.x, s0.y - s1.y);
    X[1] = make_float2(d0.x + d1.x, d0.y + d1.y);
    X[3] = make_float2(d0.x - d1.x, d0.y - d1.y);
}

__device__ __forceinline__ void stageR8(float2* zp, const int adr[8], const float2 W[7]) {
    float2 X[8], Y[8];
    #pragma unroll
    for (int j = 0; j < 8; ++j) X[j] = zp[adr[j]];
    dft8(X, Y);
    #pragma unroll
    for (int m = 1; m < 8; ++m) Y[m] = CMUL(Y[m].x, Y[m].y, W[m-1].x, W[m-1].y);
    #pragma unroll
    for (int m = 0; m < 8; ++m) zp[adr[m]] = Y[m];
}

__global__ __launch_bounds__(256) void ifft_topk(const float2* __restrict__ S,
                                                 float* __restrict__ wout,
                                                 int* __restrict__ dout) {
    __shared__ float2 zz[LSEQ];
    __shared__ float  mc[LSEQ];
    __shared__ float  pv[4];
    __shared__ int    pig[4];
    __shared__ float  topv[NDEL];
    __shared__ int    topi[NDEL];
    const int b = blockIdx.x, t = threadIdx.x;

    float2 WA[7], WB[7], WC[7];
    {
        float sn, cs;
        __sincosf(-6.28318530717958647692f * (float)t / 2048.f, &sn, &cs);
        WA[0] = make_float2(cs, sn);
        __sincosf(-6.28318530717958647692f * (float)(t & 31) / 256.f, &sn, &cs);
        WB[0] = make_float2(cs, sn);
        __sincosf(-6.28318530717958647692f * (float)(t & 3) / 32.f, &sn, &cs);
        WC[0] = make_float2(cs, sn);
        #pragma unroll
        for (int m = 1; m < 7; ++m) {
            WA[m] = CMUL(WA[m-1].x, WA[m-1].y, WA[0].x, WA[0].y);
            WB[m] = CMUL(WB[m-1].x, WB[m-1].y, WB[0].x, WB[0].y);
            WC[m] = CMUL(WC[m-1].x, WC[m-1].y, WC[0].x, WC[0].y);
        }
    }
    const int sbB   = (t >> 5) * 256 + (t & 31);
    const int baseC = (t >> 2) * 32 + (t & 3);
    int adrB[8], adrC[8], adrD[8];
    #pragma unroll
    for (int n = 0; n < 8; ++n) {
        adrB[n] = SWZ(sbB + 32 * n);
        adrC[n] = SWZ(baseC + 4 * n);
        adrD[n] = SWZ(8 * t + n);
    }

    #pragma unroll
    for (int u = 0; u < 4; ++u) {
        const int j = t + 256 * u;
        const float2 s = S[b * 1024 + j];
        if (j == 0) {
            zz[0] = make_float2(s.x, 0.f);
            zz[2] = make_float2(s.y, 0.f);
        } else {
            zz[pof(j)]        = s;
            zz[pof(2048 - j)] = make_float2(s.x, -s.y);
        }
    }
    __syncthreads();

    float2 X[8], Y[8];
    #pragma unroll
    for (int j = 0; j < 8; ++j) {
        const float2 s = zz[pof(t + 256 * j)];
        X[j] = make_float2(s.x, -s.y);
    }
    __syncthreads();

    dft8(X, Y);
    #pragma unroll
    for (int m = 1; m < 8; ++m) Y[m] = CMUL(Y[m].x, Y[m].y, WA[m-1].x, WA[m-1].y);
    #pragma unroll
    for (int m = 0; m < 8; ++m) zz[SWZ(m * 256 + t)] = Y[m];
    __syncthreads();

    stageR8(zz, adrB, WB);
    __syncthreads();
    stageR8(zz, adrC, WC);
    __syncthreads();

    {
        float2 xin[8];
        #pragma unroll
        for (int j = 0; j < 8; ++j) xin[j] = zz[adrD[j]];
        dft4(&xin[0], &X[0]);
        dft4(&xin[4], &X[4]);
    }

    const float scale = 1.0f / ((float)LSEQ * (float)(NH * ND));
    #pragma unroll
    for (int cc = 0; cc < 8; ++cc) mc[fofp(8 * t + cc)] = X[cc].x * scale;
    __syncthreads();

    const int lane = t & 63, wv = t >> 6;
    for (int it = 0; it < NDEL; ++it) {
        float bv = -3e38f; int bix = 0;
        #pragma unroll
        for (int u = 0; u < 8; ++u) {
            const int idx = t + 256 * u;
            const float v = mc[idx];
            if (v > bv || (v == bv && idx < bix)) { bv = v; bix = idx; }
        }
        #pragma unroll
        for (int off = 32; off; off >>= 1) {
            const float ov = __shfl_xor(bv, off);
            const int   oi = __shfl_xor(bix, off);
            if (ov > bv || (ov == bv && oi < bix)) { bv = ov; bix = oi; }
        }
        if (lane == 0) { pv[wv] = bv; pig[wv] = bix; }
        __syncthreads();
        if (t < 64) {
            float v = (t < 4) ? pv[t] : -3e38f;
            int  ii = (t < 4) ? pig[t] : 0;
            #pragma unroll
            for (int off = 2; off; off >>= 1) {
                const float ov = __shfl_xor(v, off);
                const int   oi = __shfl_xor(ii, off);
                if (ov > v || (ov == v && oi < ii)) { v = ov; ii = oi; }
            }
            if (t == 0) { topv[it] = v; topi[it] = ii; mc[ii] = -3e38f; }
        }
        __syncthreads();
    }

    if (t == 0) {
        const float m = topv[0];
        float e[NDEL], sum = 0.f;
        for (int i = 0; i < NDEL; ++i) { e[i] = __expf(topv[i] - m); sum += e[i]; }
        const float inv = 1.0f / sum;
        for (int i = 0; i < NDEL; ++i) {
            wout[b * NDEL + i] = e[i] * inv;
            dout[b * NDEL + i] = topi[i];
        }
    }
}

// ---------------------------------------------------------------------------
// Kernel C: out[b,h,t,d] = sum_k w[b,k] * v[b,h,(t+delay[b,k]) & 2047, d]
// XCD swizzle: 128 t-tiles of one (b,h) share an XCD (v slice L2-resident).
// ---------------------------------------------------------------------------
__global__ __launch_bounds__(256) void gather_out(const float* __restrict__ v,
                                                  const float* __restrict__ w,
                                                  const int* __restrict__ delay,
                                                  float* __restrict__ out) {
    const int bi  = blockIdx.x;          // 8192 = 64 bh * 128 tiles
    const int xcd = bi & 7;
    const int s   = bi >> 3;
    const int bh  = xcd * 8 + (s >> 7);
    const int bt  = s & 127;
    const int b   = bh >> 3;
    const int tid = threadIdx.x;

    __shared__ float sw_[NDEL];
    __shared__ int   sd_[NDEL];
    if (tid < NDEL) {
        sw_[tid] = w[b * NDEL + tid];
        sd_[tid] = delay[b * NDEL + tid];
    }
    __syncthreads();

    const float* vb = v + (size_t)bh * LSEQ * ND;
    float*       ob = out + (size_t)bh * LSEQ * ND;

    const int row = tid >> 4;
    const int col = (tid & 15) * 4;
    const int t   = bt * 16 + row;

    float4 acc = make_float4(0.f, 0.f, 0.f, 0.f);
    #pragma unroll
    for (int kk = 0; kk < NDEL; ++kk) {
        const int r = (t + sd_[kk]) & (LSEQ - 1);
        const float4 vv = *(const float4*)(vb + (size_t)r * ND + col);
        const float wv = sw_[kk];
        acc.x += wv * vv.x; acc.y += wv * vv.y;
        acc.z += wv * vv.z; acc.w += wv * vv.w;
    }
    *(float4*)(ob + (size_t)t * ND + col) = acc;
}

// ---------------------------------------------------------------------------
extern "C" void kernel_launch(void* const* d_in, const int* in_sizes, int n_in,
                              void* d_out, int out_size, void* d_ws, size_t ws_size,
                              hipStream_t stream) {
    const float* q = (const float*)d_in[0];
    const float* k = (const float*)d_in[1];
    const float* v = (const float*)d_in[2];
    float* out = (float*)d_out;

    float2* Pc    = (float2*)((char*)d_ws + WS_P_OFF);
    float*  w     = (float*)((char*)d_ws + WS_W_OFF);
    int*    delay = (int*)((char*)d_ws + WS_DELAY_OFF);

    fft_corr<<<dim3(1024), dim3(256), 0, stream>>>(q, k, Pc);
    reduce_S<<<dim3(128), dim3(256), 0, stream>>>(Pc);
    ifft_topk<<<dim3(NB), dim3(256), 0, stream>>>(Pc, w, delay);  // part 0 = S
    gather_out<<<dim3(NB * NH * 128), dim3(256), 0, stream>>>(v, w, delay, out);
}